// Round 8
// baseline (159.849 us; speedup 1.0000x reference)
//
#include <hip/hip_runtime.h>

#define N_NODES 50000
#define N_EDGES 800000
#define D 64
#define NB 196                 // ceil(50000/256)
#define NPAD (NB * 256)        // 50176, zero-padded degree region
#define NBLK_MM (N_NODES / 16)                 // 3125 matmul tiles
#define NBLK_DEG ((N_EDGES / 4 + 255) / 256)   // 782 deg chunks (4 edges/thread)

typedef _Float16 half4 __attribute__((ext_vector_type(4)));

// ---- 1+2 fused & interleaved: first 1564 blocks alternate mm/deg ----
// deg side: 4 edges/thread, 4 INDEPENDENT atomics in flight per thread
// (int4 load + int4 rank store). mm side: VALU-bound tile. Co-residency from
// t=0 => cost ~ max(streams), and the 782 deg blocks retire 4x fewer blocks
// than R7's 1-edge/thread variant.
__global__ __launch_bounds__(256) void k_mm_degrank(const float* __restrict__ x,
                                                    const float* __restrict__ W,
                                                    _Float16* __restrict__ xwh,
                                                    const int* __restrict__ col,
                                                    int* __restrict__ deg,
                                                    int* __restrict__ rank) {
    __shared__ float Wl[D * D];
    __shared__ float xl[16 * D];
    int bid = blockIdx.x;
    bool isdeg;
    int wid;
    if (bid < 2 * NBLK_DEG) { isdeg = bid & 1; wid = bid >> 1; }
    else                    { isdeg = false;   wid = bid - NBLK_DEG; }
    if (isdeg) {
        int e4 = wid * 256 + threadIdx.x;
        if (e4 < N_EDGES / 4) {
            int4 c = ((const int4*)col)[e4];
            int4 k;
            k.x = atomicAdd(&deg[c.x], 1);
            k.y = atomicAdd(&deg[c.y], 1);
            k.z = atomicAdd(&deg[c.z], 1);
            k.w = atomicAdd(&deg[c.w], 1);
            ((int4*)rank)[e4] = k;
        }
        return;
    }
    int tid = threadIdx.x;
#pragma unroll
    for (int i = tid; i < D * D / 4; i += 256)
        ((float4*)Wl)[i] = ((const float4*)W)[i];
    int r0 = wid * 16;
    ((float4*)xl)[tid] = ((const float4*)(x + (size_t)r0 * D))[tid];
    __syncthreads();
    int c  = tid & 63;
    int rg = tid >> 6;                 // rows rg, rg+4, rg+8, rg+12
    float acc[4] = {0.f, 0.f, 0.f, 0.f};
    for (int k = 0; k < D; ++k) {
        float w = Wl[k * D + c];
#pragma unroll
        for (int q = 0; q < 4; ++q)
            acc[q] = fmaf(xl[(rg + 4 * q) * D + k], w, acc[q]);
    }
#pragma unroll
    for (int q = 0; q < 4; ++q)
        xwh[(size_t)(r0 + rg + 4 * q) * D + c] = (_Float16)acc[q];
}

// ---- 3a. per-block sums of deg; also dis = rsqrt(deg+1) ----
__global__ __launch_bounds__(256) void k_scan1(const int* __restrict__ deg,
                                               float* __restrict__ dis,
                                               int* __restrict__ bsum) {
    __shared__ int s[256];
    int i = blockIdx.x * 256 + threadIdx.x;
    int d = deg[i];
    dis[i] = rsqrtf((float)(d + 1));
    s[threadIdx.x] = d;
    __syncthreads();
    for (int off = 128; off > 0; off >>= 1) {
        if (threadIdx.x < off) s[threadIdx.x] += s[threadIdx.x + off];
        __syncthreads();
    }
    if (threadIdx.x == 0) bsum[blockIdx.x] = s[0];
}

// ---- 3b. rowptr: every block re-scans the 196 block sums in LDS ----
__global__ __launch_bounds__(256) void k_scan3(const int* __restrict__ deg,
                                               const int* __restrict__ bsum,
                                               int* __restrict__ rowptr) {
    __shared__ int s[256];
    __shared__ int sb[256];
    int t = threadIdx.x;
    int i = blockIdx.x * 256 + t;
    int d = deg[i];
    s[t] = d;
    sb[t] = (t < NB) ? bsum[t] : 0;
    __syncthreads();
    for (int off = 1; off < 256; off <<= 1) {
        int u1 = (t >= off) ? s[t - off] : 0;
        int u2 = (t >= off) ? sb[t - off] : 0;
        __syncthreads();
        s[t] += u1;
        sb[t] += u2;
        __syncthreads();
    }
    int boff = (blockIdx.x == 0) ? 0 : sb[blockIdx.x - 1];
    rowptr[i] = boff + s[t] - d;
}

// ---- 4. bucket: edata[rowptr[c]+rank] = {src, dis[src]} — no atomics ----
__global__ __launch_bounds__(256) void k_bucket(const int* __restrict__ ei,
                                                const int* __restrict__ rowptr,
                                                const int* __restrict__ rank,
                                                const float* __restrict__ dis,
                                                int2* __restrict__ edata) {
    int e4 = blockIdx.x * blockDim.x + threadIdx.x;
    if (e4 < N_EDGES / 4) {
        int4 r = ((const int4*)ei)[e4];
        int4 c = ((const int4*)(ei + N_EDGES))[e4];
        int4 k = ((const int4*)rank)[e4];
        int2 d0 = {r.x, __float_as_int(dis[r.x])};
        int2 d1 = {r.y, __float_as_int(dis[r.y])};
        int2 d2 = {r.z, __float_as_int(dis[r.z])};
        int2 d3 = {r.w, __float_as_int(dis[r.w])};
        edata[rowptr[c.x] + k.x] = d0;
        edata[rowptr[c.y] + k.y] = d1;
        edata[rowptr[c.z] + k.z] = d2;
        edata[rowptr[c.w] + k.w] = d3;
    }
}

// ---- 5. gather + self-loop + bias + relu ----
// One wave per node, lane=(g:2)(c4:4). Software-pipelined: next pair's edata
// is prefetched before the current pair's row loads (overlaps the 2-hop chain).
__global__ __launch_bounds__(256) void k_gather(const int* __restrict__ rowptr,
                                                const int2* __restrict__ edata,
                                                const _Float16* __restrict__ xwh,
                                                const float* __restrict__ dis,
                                                const float* __restrict__ b,
                                                float* __restrict__ out) {
    int node = blockIdx.x * 4 + (threadIdx.x >> 6);
    int lane = threadIdx.x & 63;
    int g  = lane >> 4;                // 0..3 edge subgroup
    int c4 = lane & 15;                // channel quad index
    int beg = rowptr[node], end = rowptr[node + 1];
    float4 acc0 = {0.f, 0.f, 0.f, 0.f};
    float4 acc1 = {0.f, 0.f, 0.f, 0.f};
    int j = beg + g;
    int2 e0, e1;
    if (j + 4 < end) { e0 = edata[j]; e1 = edata[j + 4]; }
    // steady state: consume (e0,e1), prefetch next pair
    for (; j + 12 < end; j += 8) {
        int2 n0 = edata[j + 8];
        int2 n1 = edata[j + 12];
        float s0 = __int_as_float(e0.y);
        float s1 = __int_as_float(e1.y);
        half4 v0 = *(const half4*)(xwh + (size_t)e0.x * D + c4 * 4);
        half4 v1 = *(const half4*)(xwh + (size_t)e1.x * D + c4 * 4);
        acc0.x = fmaf(s0, (float)v0.x, acc0.x);
        acc0.y = fmaf(s0, (float)v0.y, acc0.y);
        acc0.z = fmaf(s0, (float)v0.z, acc0.z);
        acc0.w = fmaf(s0, (float)v0.w, acc0.w);
        acc1.x = fmaf(s1, (float)v1.x, acc1.x);
        acc1.y = fmaf(s1, (float)v1.y, acc1.y);
        acc1.z = fmaf(s1, (float)v1.z, acc1.z);
        acc1.w = fmaf(s1, (float)v1.w, acc1.w);
        e0 = n0; e1 = n1;
    }
    // drain preloaded pair (exit guarantees j+4>=end afterwards)
    if (j + 4 < end) {
        float s0 = __int_as_float(e0.y);
        float s1 = __int_as_float(e1.y);
        half4 v0 = *(const half4*)(xwh + (size_t)e0.x * D + c4 * 4);
        half4 v1 = *(const half4*)(xwh + (size_t)e1.x * D + c4 * 4);
        acc0.x = fmaf(s0, (float)v0.x, acc0.x);
        acc0.y = fmaf(s0, (float)v0.y, acc0.y);
        acc0.z = fmaf(s0, (float)v0.z, acc0.z);
        acc0.w = fmaf(s0, (float)v0.w, acc0.w);
        acc1.x = fmaf(s1, (float)v1.x, acc1.x);
        acc1.y = fmaf(s1, (float)v1.y, acc1.y);
        acc1.z = fmaf(s1, (float)v1.z, acc1.z);
        acc1.w = fmaf(s1, (float)v1.w, acc1.w);
        j += 8;
    }
    // at most one leftover edge per subgroup
    if (j < end) {
        int2 e = edata[j];
        float s = __int_as_float(e.y);
        half4 v = *(const half4*)(xwh + (size_t)e.x * D + c4 * 4);
        acc0.x = fmaf(s, (float)v.x, acc0.x);
        acc0.y = fmaf(s, (float)v.y, acc0.y);
        acc0.z = fmaf(s, (float)v.z, acc0.z);
        acc0.w = fmaf(s, (float)v.w, acc0.w);
    }
    acc0.x += acc1.x; acc0.y += acc1.y; acc0.z += acc1.z; acc0.w += acc1.w;
#pragma unroll
    for (int m = 16; m <= 32; m <<= 1) {
        acc0.x += __shfl_xor(acc0.x, m, 64);
        acc0.y += __shfl_xor(acc0.y, m, 64);
        acc0.z += __shfl_xor(acc0.z, m, 64);
        acc0.w += __shfl_xor(acc0.w, m, 64);
    }
    if (g == 0) {
        float dc = dis[node];
        half4 xv = *(const half4*)(xwh + (size_t)node * D + c4 * 4);
        float4 bv = *(const float4*)(b + c4 * 4);
        float4 o;
        o.x = dc * fmaf(dc, (float)xv.x, acc0.x) + bv.x;
        o.y = dc * fmaf(dc, (float)xv.y, acc0.y) + bv.y;
        o.z = dc * fmaf(dc, (float)xv.z, acc0.z) + bv.z;
        o.w = dc * fmaf(dc, (float)xv.w, acc0.w) + bv.w;
        o.x = o.x > 0.f ? o.x : 0.f;
        o.y = o.y > 0.f ? o.y : 0.f;
        o.z = o.z > 0.f ? o.z : 0.f;
        o.w = o.w > 0.f ? o.w : 0.f;
        *(float4*)(out + (size_t)node * D + c4 * 4) = o;
    }
}

extern "C" void kernel_launch(void* const* d_in, const int* in_sizes, int n_in,
                              void* d_out, int out_size, void* d_ws, size_t ws_size,
                              hipStream_t stream) {
    const float* x  = (const float*)d_in[0];
    const int*   ei = (const int*)d_in[1];   // [2, E] row-major, int32
    const float* W  = (const float*)d_in[2];
    const float* b  = (const float*)d_in[3];
    float* out = (float*)d_out;

    char* ws = (char*)d_ws;
    size_t off = 0;
    _Float16* xwh = (_Float16*)(ws + off); off += (size_t)N_NODES * D * sizeof(_Float16);
    int*   deg    = (int*)  (ws + off); off += (size_t)NPAD * sizeof(int);
    float* dis    = (float*)(ws + off); off += (size_t)NPAD * sizeof(float);
    int*   rowptr = (int*)  (ws + off); off += (size_t)(NPAD + 16) * sizeof(int);
    int*   bsum   = (int*)  (ws + off); off += (size_t)256 * sizeof(int);
    int*   rank   = (int*)  (ws + off); off += (size_t)N_EDGES * sizeof(int);
    int2*  edata  = (int2*) (ws + off); off += (size_t)N_EDGES * sizeof(int2);

    hipMemsetAsync(deg, 0, (size_t)NPAD * sizeof(int), stream);

    k_mm_degrank<<<NBLK_MM + NBLK_DEG, 256, 0, stream>>>(x, W, xwh, ei + N_EDGES, deg, rank);
    k_scan1<<<NB, 256, 0, stream>>>(deg, dis, bsum);
    k_scan3<<<NB, 256, 0, stream>>>(deg, bsum, rowptr);
    k_bucket<<<(N_EDGES / 4 + 255) / 256, 256, 0, stream>>>(ei, rowptr, rank, dis, edata);
    k_gather<<<N_NODES / 4, 256, 0, stream>>>(rowptr, edata, xwh, dis, b, out);
}